// Round 1
// baseline (1593.904 us; speedup 1.0000x reference)
//
#include <hip/hip_runtime.h>
#include <hip/hip_bf16.h>

typedef __attribute__((ext_vector_type(4))) float f32x4;
typedef __attribute__((ext_vector_type(8))) short short8;
typedef __attribute__((ext_vector_type(8))) unsigned short ushort8;
typedef __attribute__((ext_vector_type(4))) unsigned short ushort4_t;

#define B_    128
#define N_    4096
#define DIN   256
#define D_    256
#define NHD   4
#define DH    64
#define HMLP  1024
#define NSPLIT 8

__device__ inline float bf2f(unsigned short u){
  union{unsigned int i; float f;} c; c.i = ((unsigned int)u)<<16; return c.f;
}
__device__ inline unsigned short f2bf(float f){
  union{float f; unsigned int i;} c; c.f = f;
  unsigned int x = c.i;
  return (unsigned short)((x + 0x7fffu + ((x>>16)&1u)) >> 16);
}
__device__ inline float sigm(float s){ return 1.0f/(1.0f+__expf(-s)); }

// block = 256 threads (4 waves). Full block sum.
__device__ inline float blkSum(float v, float* s4){
  v += __shfl_xor(v,1);  v += __shfl_xor(v,2);  v += __shfl_xor(v,4);
  v += __shfl_xor(v,8);  v += __shfl_xor(v,16); v += __shfl_xor(v,32);
  int lane = threadIdx.x & 63, w = threadIdx.x >> 6;
  __syncthreads();
  if (lane==0) s4[w] = v;
  __syncthreads();
  return s4[0]+s4[1]+s4[2]+s4[3];
}

// ---------------- prep: weight transposes / bf16 casts --------------------
__global__ __launch_bounds__(256) void k_prep(
    const float* __restrict__ Wk, const float* __restrict__ Wv,
    const float* __restrict__ Wih, const float* __restrict__ Whh,
    const float* __restrict__ W1, const float* __restrict__ W2,
    const float* __restrict__ Wq,
    unsigned short* __restrict__ WkvT, unsigned short* __restrict__ WihT,
    unsigned short* __restrict__ WhhT, unsigned short* __restrict__ W1b,
    unsigned short* __restrict__ W2b, unsigned short* __restrict__ Wqb){
  int idx = blockIdx.x*256 + threadIdx.x;          // 0 .. 262143
  if (idx < 512*256){                               // WkvT [512][256], k pre-scaled by sqrt(4)=2
    int nn = idx>>8, k = idx&255;
    float v = (nn<256) ? 2.0f*Wk[k*256+nn] : Wv[k*256+(nn-256)];
    WkvT[idx] = f2bf(v);
  }
  if (idx < 256*768){                               // WihT/WhhT [256][768]
    int k = idx/768, j = idx - k*768;
    WihT[idx] = f2bf(Wih[j*256+k]);
    WhhT[idx] = f2bf(Whh[j*256+k]);
  }
  if (idx < 256*1024){ W1b[idx] = f2bf(W1[idx]); W2b[idx] = f2bf(W2[idx]); }
  if (idx < 256*256){ Wqb[idx] = f2bf(Wq[idx]); }
}

// ---------------- LN over inputs -> x bf16 --------------------------------
__global__ __launch_bounds__(256) void k_ln_in(
    const float* __restrict__ in, const float* __restrict__ g,
    const float* __restrict__ b, unsigned short* __restrict__ x){
  size_t row = (size_t)blockIdx.x*4 + (threadIdx.x>>6);
  int lane = threadIdx.x & 63;
  float4 v = reinterpret_cast<const float4*>(in + row*256)[lane];
  float s = v.x+v.y+v.z+v.w;
  float q = v.x*v.x+v.y*v.y+v.z*v.z+v.w*v.w;
  #pragma unroll
  for(int o=1;o<64;o<<=1){ s += __shfl_xor(s,o); q += __shfl_xor(q,o); }
  float mu = s*(1.0f/256.0f);
  float var = q*(1.0f/256.0f) - mu*mu;
  float rs = rsqrtf(var + 1e-5f);
  float4 gg = reinterpret_cast<const float4*>(g)[lane];
  float4 bb = reinterpret_cast<const float4*>(b)[lane];
  ushort4_t o4;
  o4.x = f2bf((v.x-mu)*rs*gg.x + bb.x);
  o4.y = f2bf((v.y-mu)*rs*gg.y + bb.y);
  o4.z = f2bf((v.z-mu)*rs*gg.z + bb.z);
  o4.w = f2bf((v.w-mu)*rs*gg.w + bb.w);
  reinterpret_cast<ushort4_t*>(x + row*256)[lane] = o4;
}

// ---------------- GEMM: x[524288,256] @ Wkv[256,512] -> k,v bf16 ----------
// 128x128 tile, BK=64, 4 waves each 64x64, mfma 16x16x32 bf16.
#define LDAP 72   // padded LDS row (elems): 144B rows -> only 2-way bank alias (free)
__global__ __launch_bounds__(256) void k_gemm_kv(
    const unsigned short* __restrict__ X, const unsigned short* __restrict__ WT,
    unsigned short* __restrict__ kb, unsigned short* __restrict__ vb){
  __shared__ unsigned short As[128*LDAP];
  __shared__ unsigned short Bs[128*LDAP];
  int tid = threadIdx.x, wid = tid>>6, lane = tid&63;
  int wr = wid>>1, wc = wid&1;
  int nt = blockIdx.x, mt = blockIdx.y;
  const unsigned short* Xb = X  + (size_t)mt*128*256;
  const unsigned short* Wb = WT + (size_t)nt*128*256;
  f32x4 acc[4][4] = {};
  ushort8 ra[4], rb[4];
  #pragma unroll
  for(int i=0;i<4;i++){
    int c = i*256 + tid; int row = c>>3, kc = c&7;
    ra[i] = *reinterpret_cast<const ushort8*>(Xb + (size_t)row*256 + kc*8);
    rb[i] = *reinterpret_cast<const ushort8*>(Wb + (size_t)row*256 + kc*8);
  }
  int r16 = lane&15, kg = lane>>4;
  for(int it=0; it<4; ++it){
    __syncthreads();
    #pragma unroll
    for(int i=0;i<4;i++){
      int c = i*256 + tid; int row = c>>3, kc = c&7;
      *reinterpret_cast<ushort8*>(As + row*LDAP + kc*8) = ra[i];
      *reinterpret_cast<ushort8*>(Bs + row*LDAP + kc*8) = rb[i];
    }
    __syncthreads();
    if (it<3){
      int k0 = (it+1)*64;
      #pragma unroll
      for(int i=0;i<4;i++){
        int c = i*256 + tid; int row = c>>3, kc = c&7;
        ra[i] = *reinterpret_cast<const ushort8*>(Xb + (size_t)row*256 + k0 + kc*8);
        rb[i] = *reinterpret_cast<const ushort8*>(Wb + (size_t)row*256 + k0 + kc*8);
      }
    }
    #pragma unroll
    for(int kk=0;kk<2;kk++){
      short8 af[4], bf[4];
      #pragma unroll
      for(int mi=0;mi<4;mi++)
        af[mi] = *reinterpret_cast<const short8*>(As + (wr*64+mi*16+r16)*LDAP + kk*32 + kg*8);
      #pragma unroll
      for(int ni=0;ni<4;ni++)
        bf[ni] = *reinterpret_cast<const short8*>(Bs + (wc*64+ni*16+r16)*LDAP + kk*32 + kg*8);
      #pragma unroll
      for(int mi=0;mi<4;mi++)
        #pragma unroll
        for(int ni=0;ni<4;ni++)
          acc[mi][ni] = __builtin_amdgcn_mfma_f32_16x16x32_bf16(af[mi], bf[ni], acc[mi][ni], 0,0,0);
    }
  }
  // epilogue: C/D mapping col=lane&15, row=(lane>>4)*4+reg  [measured m89]
  int rg = lane>>4;
  #pragma unroll
  for(int mi=0;mi<4;mi++){
    #pragma unroll
    for(int ni=0;ni<4;ni++){
      int col = nt*128 + wc*64 + ni*16 + r16;
      int h = (col&255)>>6, d = col&63;
      #pragma unroll
      for(int r=0;r<4;r++){
        int row = mt*128 + wr*64 + mi*16 + rg*4 + r;
        int b = row>>12, n = row&4095;
        size_t off = ((size_t)((b*4+h)*4096 + n))*64 + d;
        unsigned short val = f2bf(acc[mi][ni][r]);
        if (col < 256) kb[off] = val; else vb[off] = val;
      }
    }
  }
}

// ---------------- init: rep0 = mu + exp(.5 lv)*eps ; q0 -------------------
__global__ __launch_bounds__(256) void k_init(
    const float* __restrict__ eps, const float* __restrict__ mu0,
    const float* __restrict__ lv0, const float* __restrict__ sg,
    const float* __restrict__ sb, const unsigned short* __restrict__ Wqb,
    float* __restrict__ rep, float* __restrict__ q){
  __shared__ float s4[4]; __shared__ float xq[256];
  int b = blockIdx.x, c = threadIdx.x;
  float r0 = mu0[c] + __expf(0.5f*lv0[c]) * eps[b*256+c];
  rep[b*256+c] = r0;
  float mu = blkSum(r0, s4) * (1.0f/256.0f);
  float var = blkSum((r0-mu)*(r0-mu), s4) * (1.0f/256.0f);
  float rs = rsqrtf(var + 1e-5f);
  xq[c] = (r0-mu)*rs*sg[c] + sb[c];
  __syncthreads();
  float acc = 0.f;
  for(int k=0;k<256;k++) acc += xq[k]*bf2f(Wqb[k*256+c]);
  q[b*256+c] = acc;
}

// ---------------- attention: one pass, split partials ---------------------
__global__ __launch_bounds__(256) void k_attn(
    const unsigned short* __restrict__ kbuf, const unsigned short* __restrict__ vbuf,
    const float* __restrict__ q, float* __restrict__ att_part,
    float* __restrict__ ws_part, float* __restrict__ w_out, int write_w){
  int split = blockIdx.x;          // 0..7
  int bh    = blockIdx.y;          // 0..511
  int tid = threadIdx.x, wid = tid>>6, lane = tid&63;
  int grp = lane>>3, sub = lane&7;
  float qv[8];
  #pragma unroll
  for(int j=0;j<8;j++) qv[j] = q[bh*64 + sub*8 + j];
  const unsigned short* kp = kbuf + (size_t)bh*N_*64;
  const unsigned short* vp = vbuf + (size_t)bh*N_*64;
  float acc[8] = {0,0,0,0,0,0,0,0};
  float wsum = 0.f;
  int nbase = split*512 + wid*128;
  for(int it=0; it<16; ++it){
    int n = nbase + it*8 + grp;
    size_t off = (size_t)n*64 + sub*8;
    ushort8 k8 = *reinterpret_cast<const ushort8*>(kp + off);
    ushort8 v8 = *reinterpret_cast<const ushort8*>(vp + off);
    float s = 0.f;
    #pragma unroll
    for(int j=0;j<8;j++) s += bf2f(k8[j]) * qv[j];
    s += __shfl_xor(s,1); s += __shfl_xor(s,2); s += __shfl_xor(s,4);
    float w = sigm(s) + 1e-8f;
    wsum += w;
    #pragma unroll
    for(int j=0;j<8;j++) acc[j] += w * bf2f(v8[j]);
    if (write_w && sub==0) w_out[(size_t)bh*N_ + n] = w;
  }
  #pragma unroll
  for(int o=8;o<64;o<<=1){
    #pragma unroll
    for(int j=0;j<8;j++) acc[j] += __shfl_xor(acc[j], o);
    wsum += __shfl_xor(wsum, o);
  }
  __shared__ float lacc[4][64];
  __shared__ float lws[4];
  if (lane < 8){
    #pragma unroll
    for(int j=0;j<8;j++) lacc[wid][lane*8+j] = acc[j];
    if (lane==0) lws[wid] = wsum;
  }
  __syncthreads();
  if (tid < 64){
    float a = lacc[0][tid]+lacc[1][tid]+lacc[2][tid]+lacc[3][tid];
    att_part[((size_t)split*512 + bh)*64 + tid] = a;
  } else if (tid == 64){
    ws_part[split*512 + bh] = lws[0]+lws[1]+lws[2]+lws[3];
  }
}

// ---------------- GRU + residual-LN ---------------------------------------
__global__ __launch_bounds__(256) void k_gru(
    const float* __restrict__ att_part, const float* __restrict__ ws_part,
    const float* __restrict__ rep, const unsigned short* __restrict__ WihT,
    const unsigned short* __restrict__ WhhT, const float* __restrict__ bih,
    const float* __restrict__ bhh, const float* __restrict__ lng,
    const float* __restrict__ lnb, float* __restrict__ rep_tmp,
    float* __restrict__ lnres, float* __restrict__ wsum_tot){
  __shared__ float att_s[256], rep_s[256], s4[4];
  int b = blockIdx.x, c = threadIdx.x;
  int h = c>>6;
  float au = 0.f, ws = 0.f;
  #pragma unroll
  for(int s=0;s<NSPLIT;s++){
    au += att_part[((size_t)s*512 + b*4+h)*64 + (c&63)];
    ws += ws_part[s*512 + b*4+h];
  }
  att_s[c] = au/ws;
  rep_s[c] = rep[b*256+c];
  if ((c&63)==0) wsum_tot[b*4+h] = ws;
  __syncthreads();
  float dir=0,dhr=0,diz=0,dhz=0,dig=0,dhg=0;
  for(int k=0;k<256;k++){
    float a = att_s[k], r = rep_s[k];
    const unsigned short* wi = WihT + k*768;
    const unsigned short* wh = WhhT + k*768;
    dir += a*bf2f(wi[c]);      dhr += r*bf2f(wh[c]);
    diz += a*bf2f(wi[256+c]);  dhz += r*bf2f(wh[256+c]);
    dig += a*bf2f(wi[512+c]);  dhg += r*bf2f(wh[512+c]);
  }
  float rr = sigm(dir+bih[c]     + dhr+bhh[c]);
  float zz = sigm(diz+bih[256+c] + dhz+bhh[256+c]);
  float gg = tanhf(dig+bih[512+c] + rr*(dhg+bhh[512+c]));
  float nw = (1.f-zz)*gg + zz*rep_s[c];
  rep_tmp[b*256+c] = nw;
  float mu = blkSum(nw, s4)*(1.0f/256.0f);
  float var = blkSum((nw-mu)*(nw-mu), s4)*(1.0f/256.0f);
  float rs = rsqrtf(var+1e-5f);
  lnres[b*256+c] = (nw-mu)*rs*lng[c]+lnb[c];
}

// ---------------- MLP residual + next-q -----------------------------------
__global__ __launch_bounds__(256) void k_mlp(
    const float* __restrict__ lnres, const float* __restrict__ rep_tmp,
    const unsigned short* __restrict__ W1b, const unsigned short* __restrict__ W2b,
    const float* __restrict__ b2, const unsigned short* __restrict__ Wqb,
    const float* __restrict__ sg, const float* __restrict__ sb,
    float* __restrict__ rep, float* __restrict__ q,
    float* __restrict__ out_rep, int last){
  __shared__ float ln_s[256]; __shared__ float h1_s[1024];
  __shared__ float s4[4]; __shared__ float xq[256];
  int b = blockIdx.x, c = threadIdx.x;
  ln_s[c] = lnres[b*256+c];
  __syncthreads();
  #pragma unroll
  for(int p=0;p<4;p++){
    int j = p*256+c;
    float acc = 0.f;
    for(int k=0;k<256;k++) acc += ln_s[k]*bf2f(W1b[k*1024+j]);
    h1_s[j] = fmaxf(acc, 0.f);
  }
  __syncthreads();
  float acc = 0.f;
  for(int k=0;k<1024;k++) acc += h1_s[k]*bf2f(W2b[k*256+c]);
  float rn = rep_tmp[b*256+c] + acc + b2[c];
  rep[b*256+c] = rn;
  if (last){ out_rep[b*256+c] = rn; return; }
  float mu = blkSum(rn, s4)*(1.0f/256.0f);
  float var = blkSum((rn-mu)*(rn-mu), s4)*(1.0f/256.0f);
  float rs = rsqrtf(var+1e-5f);
  xq[c] = (rn-mu)*rs*sg[c]+sb[c];
  __syncthreads();
  float qa = 0.f;
  for(int k=0;k<256;k++) qa += xq[k]*bf2f(Wqb[k*256+c]);
  q[b*256+c] = qa;
}

// ---------------- final w output ------------------------------------------
__global__ __launch_bounds__(256) void k_wout(
    const float* __restrict__ w_buf, const float* __restrict__ wsum_tot,
    float* __restrict__ out){
  int idx = blockIdx.x*256 + threadIdx.x;     // 0..524287
  int b = idx>>12, n = idx&4095;
  float s = 0.f;
  #pragma unroll
  for(int h=0;h<4;h++)
    s += w_buf[(size_t)(b*4+h)*N_ + n] / wsum_tot[b*4+h];
  out[idx] = s;
}

extern "C" void kernel_launch(void* const* d_in, const int* in_sizes, int n_in,
                              void* d_out, int out_size, void* d_ws, size_t ws_size,
                              hipStream_t stream){
  const float* inputs  = (const float*)d_in[0];
  const float* eps     = (const float*)d_in[1];
  const float* init_mu = (const float*)d_in[2];
  const float* init_lv = (const float*)d_in[3];
  const float* Wk      = (const float*)d_in[4];
  const float* Wv      = (const float*)d_in[5];
  const float* Wq      = (const float*)d_in[6];
  const float* ln_in_g = (const float*)d_in[7];
  const float* ln_in_b = (const float*)d_in[8];
  const float* ln_sg   = (const float*)d_in[9];
  const float* ln_sb   = (const float*)d_in[10];
  const float* ln_rg   = (const float*)d_in[11];
  const float* ln_rb   = (const float*)d_in[12];
  const float* Wih     = (const float*)d_in[13];
  const float* Whh     = (const float*)d_in[14];
  const float* bih     = (const float*)d_in[15];
  const float* bhh     = (const float*)d_in[16];
  const float* W1      = (const float*)d_in[17];
  const float* W2      = (const float*)d_in[18];
  const float* b2      = (const float*)d_in[19];

  char* ws = (char*)d_ws;
  size_t off = 0;
  auto alloc = [&](size_t bytes)->void*{
    void* p = ws + off; off += (bytes + 255) & ~(size_t)255; return p;
  };
  unsigned short* x    = (unsigned short*)alloc((size_t)524288*256*2);
  unsigned short* kb   = (unsigned short*)alloc((size_t)512*4096*64*2);
  unsigned short* vb   = (unsigned short*)alloc((size_t)512*4096*64*2);
  unsigned short* WkvT = (unsigned short*)alloc(512*256*2);
  unsigned short* WihT = (unsigned short*)alloc(256*768*2);
  unsigned short* WhhT = (unsigned short*)alloc(256*768*2);
  unsigned short* W1b  = (unsigned short*)alloc(256*1024*2);
  unsigned short* W2b  = (unsigned short*)alloc(1024*256*2);
  unsigned short* Wqb  = (unsigned short*)alloc(256*256*2);
  float* q        = (float*)alloc(512*64*4);
  float* att_part = (float*)alloc((size_t)NSPLIT*512*64*4);
  float* ws_part  = (float*)alloc(NSPLIT*512*4);
  float* wsum_tot = (float*)alloc(512*4);
  float* rep      = (float*)alloc(128*256*4);
  float* rep_tmp  = (float*)alloc(128*256*4);
  float* lnres    = (float*)alloc(128*256*4);
  float* w_buf    = (float*)alloc((size_t)512*4096*4);

  float* out_rep = (float*)d_out;
  float* out_w   = out_rep + 128*256;

  k_prep<<<1024,256,0,stream>>>(Wk,Wv,Wih,Whh,W1,W2,Wq, WkvT,WihT,WhhT,W1b,W2b,Wqb);
  k_ln_in<<<131072,256,0,stream>>>(inputs, ln_in_g, ln_in_b, x);
  k_gemm_kv<<<dim3(4,4096),256,0,stream>>>(x, WkvT, kb, vb);
  k_init<<<128,256,0,stream>>>(eps, init_mu, init_lv, ln_sg, ln_sb, Wqb, rep, q);
  for(int t=0;t<4;t++){
    int last = (t==3) ? 1 : 0;
    k_attn<<<dim3(NSPLIT,512),256,0,stream>>>(kb, vb, q, att_part, ws_part, w_buf, last);
    k_gru<<<128,256,0,stream>>>(att_part, ws_part, rep, WihT, WhhT, bih, bhh,
                                ln_rg, ln_rb, rep_tmp, lnres, wsum_tot);
    k_mlp<<<128,256,0,stream>>>(lnres, rep_tmp, W1b, W2b, b2, Wqb, ln_sg, ln_sb,
                                rep, q, out_rep, last);
  }
  k_wout<<<2048,256,0,stream>>>(w_buf, wsum_tot, out_w);
}

// Round 2
// 904.554 us; speedup vs baseline: 1.7621x; 1.7621x over previous
//
#include <hip/hip_runtime.h>
#include <hip/hip_bf16.h>

typedef __attribute__((ext_vector_type(2))) float f32x2;
typedef __attribute__((ext_vector_type(8))) unsigned short ushort8;
typedef __attribute__((ext_vector_type(4))) unsigned short ushort4_t;

#define N_    4096
#define NSPLIT 16

__device__ inline float bf2f(unsigned short u){
  union{unsigned int i; float f;} c; c.i = ((unsigned int)u)<<16; return c.f;
}
__device__ inline unsigned short f2bf(float f){
  union{float f; unsigned int i;} c; c.f = f;
  unsigned int x = c.i;
  return (unsigned short)((x + 0x7fffu + ((x>>16)&1u)) >> 16);
}
__device__ inline float sigm(float s){ return 1.0f/(1.0f+__expf(-s)); }
// unpack two bf16 packed in a dword -> f32x2 (low elem first)
__device__ inline f32x2 up2(unsigned int w){
  union{unsigned int i; float f;} lo, hi;
  lo.i = w<<16; hi.i = w & 0xffff0000u;
  f32x2 r; r.x = lo.f; r.y = hi.f; return r;
}

// block = 256 threads (4 waves). Full block sum.
__device__ inline float blkSum(float v, float* s4){
  v += __shfl_xor(v,1);  v += __shfl_xor(v,2);  v += __shfl_xor(v,4);
  v += __shfl_xor(v,8);  v += __shfl_xor(v,16); v += __shfl_xor(v,32);
  int lane = threadIdx.x & 63, w = threadIdx.x >> 6;
  __syncthreads();
  if (lane==0) s4[w] = v;
  __syncthreads();
  return s4[0]+s4[1]+s4[2]+s4[3];
}

// ---------------- prep: weight transposes / bf16 casts --------------------
__global__ __launch_bounds__(256) void k_prep(
    const float* __restrict__ Wk, const float* __restrict__ Wih,
    const float* __restrict__ Whh, const float* __restrict__ W1,
    const float* __restrict__ W2, const float* __restrict__ Wq,
    float* __restrict__ WkT, unsigned short* __restrict__ WihT,
    unsigned short* __restrict__ WhhT, unsigned short* __restrict__ W1b,
    unsigned short* __restrict__ W2b, unsigned short* __restrict__ Wqb){
  int idx = blockIdx.x*256 + threadIdx.x;          // 0 .. 262143
  if (idx < 256*256){                               // WkT[d][c] = Wk[c][d] (f32)
    int d = idx>>8, c = idx&255;
    WkT[idx] = Wk[c*256+d];
    Wqb[idx] = f2bf(Wq[idx]);
  }
  if (idx < 256*768){                               // WihT/WhhT [256 k][768 j]
    int k = idx/768, j = idx - k*768;
    WihT[idx] = f2bf(Wih[j*256+k]);
    WhhT[idx] = f2bf(Whh[j*256+k]);
  }
  if (idx < 256*1024){ W1b[idx] = f2bf(W1[idx]); W2b[idx] = f2bf(W2[idx]); }
}

// ---------------- LN over inputs -> x bf16 --------------------------------
__global__ __launch_bounds__(256) void k_ln_in(
    const float* __restrict__ in, const float* __restrict__ g,
    const float* __restrict__ b, unsigned short* __restrict__ x){
  size_t row = (size_t)blockIdx.x*4 + (threadIdx.x>>6);
  int lane = threadIdx.x & 63;
  float4 v = reinterpret_cast<const float4*>(in + row*256)[lane];
  float s = v.x+v.y+v.z+v.w;
  float q = v.x*v.x+v.y*v.y+v.z*v.z+v.w*v.w;
  #pragma unroll
  for(int o=1;o<64;o<<=1){ s += __shfl_xor(s,o); q += __shfl_xor(q,o); }
  float mu = s*(1.0f/256.0f);
  float var = q*(1.0f/256.0f) - mu*mu;
  float rs = rsqrtf(var + 1e-5f);
  float4 gg = reinterpret_cast<const float4*>(g)[lane];
  float4 bb = reinterpret_cast<const float4*>(b)[lane];
  ushort4_t o4;
  o4.x = f2bf((v.x-mu)*rs*gg.x + bb.x);
  o4.y = f2bf((v.y-mu)*rs*gg.y + bb.y);
  o4.z = f2bf((v.z-mu)*rs*gg.z + bb.z);
  o4.w = f2bf((v.w-mu)*rs*gg.w + bb.w);
  reinterpret_cast<ushort4_t*>(x + row*256)[lane] = o4;
}

// ---------------- init: rep0 = mu + exp(.5 lv)*eps ; q0 -> p0 -------------
__global__ __launch_bounds__(256) void k_init(
    const float* __restrict__ eps, const float* __restrict__ mu0,
    const float* __restrict__ lv0, const float* __restrict__ sg,
    const float* __restrict__ sb, const unsigned short* __restrict__ Wqb,
    const float* __restrict__ WkT,
    float* __restrict__ rep, float* __restrict__ p_out){
  __shared__ float s4[4]; __shared__ float xq[256]; __shared__ float q_s[256];
  int b = blockIdx.x, c = threadIdx.x;
  float r0 = mu0[c] + __expf(0.5f*lv0[c]) * eps[b*256+c];
  rep[b*256+c] = r0;
  float mu = blkSum(r0, s4) * (1.0f/256.0f);
  float df = r0 - mu;
  float var = blkSum(df*df, s4) * (1.0f/256.0f);
  float rs = rsqrtf(var + 1e-5f);
  xq[c] = df*rs*sg[c] + sb[c];
  __syncthreads();
  float a0=0,a1=0,a2=0,a3=0;
  for(int k=0;k<256;k+=4){
    a0 += xq[k  ]*bf2f(Wqb[(k  )*256+c]);
    a1 += xq[k+1]*bf2f(Wqb[(k+1)*256+c]);
    a2 += xq[k+2]*bf2f(Wqb[(k+2)*256+c]);
    a3 += xq[k+3]*bf2f(Wqb[(k+3)*256+c]);
  }
  q_s[c] = a0+a1+a2+a3;
  __syncthreads();
  #pragma unroll
  for(int h=0;h<4;h++){
    float p0=0,p1=0;
    for(int d=0;d<64;d+=2){
      p0 += WkT[(h*64+d  )*256 + c]*q_s[h*64+d  ];
      p1 += WkT[(h*64+d+1)*256 + c]*q_s[h*64+d+1];
    }
    p_out[b*1024 + h*256 + c] = 2.0f*(p0+p1);
  }
}

// ---------------- attention pass on x directly ----------------------------
// u_h = sum_n w_hn * x_n  (256-dim), ws_h = sum_n w_hn.
// 16 lanes per row, 16 c-elems per lane (two 16B chunks at c=cl*8, 128+cl*8).
__global__ __launch_bounds__(256) void k_attn(
    const unsigned short* __restrict__ x, const float* __restrict__ p,
    float* __restrict__ u_part, float* __restrict__ ws_part,
    float* __restrict__ w_out, int write_w){
  int split = blockIdx.x;          // 0..15
  int b     = blockIdx.y;          // 0..127
  int tid = threadIdx.x, wid = tid>>6, lane = tid&63;
  int rgrp = lane>>4, cl = lane&15;
  const float* pb = p + (size_t)b*1024;
  f32x2 pp[4][2][4];
  #pragma unroll
  for(int h=0;h<4;h++)
    #pragma unroll
    for(int qq=0;qq<2;qq++){
      const float4 a = *reinterpret_cast<const float4*>(pb + h*256 + qq*128 + cl*8);
      const float4 c = *reinterpret_cast<const float4*>(pb + h*256 + qq*128 + cl*8 + 4);
      pp[h][qq][0] = f32x2{a.x,a.y}; pp[h][qq][1] = f32x2{a.z,a.w};
      pp[h][qq][2] = f32x2{c.x,c.y}; pp[h][qq][3] = f32x2{c.z,c.w};
    }
  f32x2 u[4][2][4] = {};
  float wsum[4] = {0,0,0,0};
  const unsigned short* xb = x + (size_t)b*N_*256;
  for(int it=0; it<16; ++it){
    int n = (split<<8) + (it<<4) + (wid<<2) + rgrp;
    const unsigned short* xr = xb + (size_t)n*256;
    uint4 xa = *reinterpret_cast<const uint4*>(xr + cl*8);
    uint4 xc = *reinterpret_cast<const uint4*>(xr + 128 + cl*8);
    f32x2 xf[2][4];
    xf[0][0]=up2(xa.x); xf[0][1]=up2(xa.y); xf[0][2]=up2(xa.z); xf[0][3]=up2(xa.w);
    xf[1][0]=up2(xc.x); xf[1][1]=up2(xc.y); xf[1][2]=up2(xc.z); xf[1][3]=up2(xc.w);
    float w[4];
    #pragma unroll
    for(int h=0;h<4;h++){
      f32x2 d2 = xf[0][0]*pp[h][0][0];
      d2 += xf[0][1]*pp[h][0][1];
      d2 += xf[0][2]*pp[h][0][2];
      d2 += xf[0][3]*pp[h][0][3];
      d2 += xf[1][0]*pp[h][1][0];
      d2 += xf[1][1]*pp[h][1][1];
      d2 += xf[1][2]*pp[h][1][2];
      d2 += xf[1][3]*pp[h][1][3];
      float s = d2.x + d2.y;
      s += __shfl_xor(s,1); s += __shfl_xor(s,2);
      s += __shfl_xor(s,4); s += __shfl_xor(s,8);
      w[h] = sigm(s) + 1e-8f;
      wsum[h] += w[h];
    }
    #pragma unroll
    for(int h=0;h<4;h++){
      f32x2 w2; w2.x = w[h]; w2.y = w[h];
      #pragma unroll
      for(int qq=0;qq<2;qq++){
        u[h][qq][0] += w2*xf[qq][0];
        u[h][qq][1] += w2*xf[qq][1];
        u[h][qq][2] += w2*xf[qq][2];
        u[h][qq][3] += w2*xf[qq][3];
      }
    }
    if (write_w && cl==0){
      float4 wv; wv.x=w[0]; wv.y=w[1]; wv.z=w[2]; wv.w=w[3];
      *reinterpret_cast<float4*>(w_out + ((size_t)b*N_ + n)*4) = wv;
    }
  }
  // reduce across the 4 row-groups of the wave (lane bits 4,5)
  #pragma unroll
  for(int h=0;h<4;h++){
    #pragma unroll
    for(int qq=0;qq<2;qq++)
      #pragma unroll
      for(int j=0;j<4;j++){
        f32x2 v = u[h][qq][j];
        v.x += __shfl_xor(v.x,16); v.y += __shfl_xor(v.y,16);
        v.x += __shfl_xor(v.x,32); v.y += __shfl_xor(v.y,32);
        u[h][qq][j] = v;
      }
    wsum[h] += __shfl_xor(wsum[h],16);
    wsum[h] += __shfl_xor(wsum[h],32);
  }
  __shared__ float u_lds[4*4*256];
  __shared__ float ws_lds[4][4];
  if (rgrp==0){   // lanes 0..15
    #pragma unroll
    for(int h=0;h<4;h++){
      #pragma unroll
      for(int qq=0;qq<2;qq++)
        #pragma unroll
        for(int j=0;j<4;j++){
          int c = qq*128 + cl*8 + j*2;
          u_lds[wid*1024 + h*256 + c    ] = u[h][qq][j].x;
          u_lds[wid*1024 + h*256 + c + 1] = u[h][qq][j].y;
        }
      if (lane==0) ws_lds[wid][h] = wsum[h];
    }
  }
  __syncthreads();
  {
    int h = tid>>6, c0 = (tid&63)*4;
    float4 s0 = *reinterpret_cast<const float4*>(u_lds +    0 + h*256 + c0);
    float4 s1 = *reinterpret_cast<const float4*>(u_lds + 1024 + h*256 + c0);
    float4 s2 = *reinterpret_cast<const float4*>(u_lds + 2048 + h*256 + c0);
    float4 s3 = *reinterpret_cast<const float4*>(u_lds + 3072 + h*256 + c0);
    float4 r; r.x=s0.x+s1.x+s2.x+s3.x; r.y=s0.y+s1.y+s2.y+s3.y;
    r.z=s0.z+s1.z+s2.z+s3.z; r.w=s0.w+s1.w+s2.w+s3.w;
    *reinterpret_cast<float4*>(u_part + (((size_t)split*128+b)*4+h)*256 + c0) = r;
  }
  if (tid<4)
    ws_part[((size_t)split*128+b)*4 + tid] =
      ws_lds[0][tid]+ws_lds[1][tid]+ws_lds[2][tid]+ws_lds[3][tid];
}

// ---------------- fused step: u->att GEMV, GRU, LN, MLP, q, p -------------
__global__ __launch_bounds__(256) void k_step(
    const float* __restrict__ u_part, const float* __restrict__ ws_part,
    const float* __restrict__ Wv, const unsigned short* __restrict__ WihT,
    const unsigned short* __restrict__ WhhT, const float* __restrict__ bih,
    const float* __restrict__ bhh, const float* __restrict__ ln_rg,
    const float* __restrict__ ln_rb, const unsigned short* __restrict__ W1b,
    const unsigned short* __restrict__ W2b, const float* __restrict__ b2,
    const float* __restrict__ ln_sg, const float* __restrict__ ln_sb,
    const unsigned short* __restrict__ Wqb, const float* __restrict__ WkT,
    float* __restrict__ rep, float* __restrict__ p_out,
    float* __restrict__ wsum_tot, float* __restrict__ out_rep, int last){
  __shared__ float u_s[1024];
  __shared__ float att_s[256];
  __shared__ float rep_s[256];
  __shared__ float ln_s[256];
  __shared__ float h1_s[1024];
  __shared__ float q_s[256];
  __shared__ float ws_s[4];
  __shared__ float s4[4];
  int b = blockIdx.x, t = threadIdx.x;
  // stage 1: sum u over splits, ws
  {
    int h = t>>6, c0 = (t&63)*4;
    float4 acc; acc.x=0; acc.y=0; acc.z=0; acc.w=0;
    #pragma unroll
    for(int s=0;s<NSPLIT;s++){
      float4 v = *reinterpret_cast<const float4*>(u_part + (((size_t)s*128+b)*4+h)*256 + c0);
      acc.x+=v.x; acc.y+=v.y; acc.z+=v.z; acc.w+=v.w;
    }
    *reinterpret_cast<float4*>(u_s + h*256 + c0) = acc;
    if (t<4){
      float ws=0;
      #pragma unroll
      for(int s=0;s<NSPLIT;s++) ws += ws_part[((size_t)s*128+b)*4 + t];
      ws_s[t]=ws; wsum_tot[b*4+t]=ws;
    }
    rep_s[t] = rep[b*256+t];
  }
  __syncthreads();
  // stage 2: att = (u . Wv)/ws   (Wv f32, coalesced over t)
  {
    int h = t>>6;
    const float* us = u_s + h*256;
    float a0=0,a1=0,a2=0,a3=0;
    for(int c=0;c<256;c+=4){
      a0 += us[c  ]*Wv[(c  )*256+t];
      a1 += us[c+1]*Wv[(c+1)*256+t];
      a2 += us[c+2]*Wv[(c+2)*256+t];
      a3 += us[c+3]*Wv[(c+3)*256+t];
    }
    att_s[t] = (a0+a1+a2+a3)/ws_s[h];
  }
  __syncthreads();
  // stage 3: GRU
  float nw;
  {
    float dir=0,dhr=0,diz=0,dhz=0,dig=0,dhg=0;
    for(int k=0;k<256;k++){
      float a = att_s[k], r = rep_s[k];
      const unsigned short* wi = WihT + k*768;
      const unsigned short* wh = WhhT + k*768;
      dir += a*bf2f(wi[t]);      dhr += r*bf2f(wh[t]);
      diz += a*bf2f(wi[256+t]);  dhz += r*bf2f(wh[256+t]);
      dig += a*bf2f(wi[512+t]);  dhg += r*bf2f(wh[512+t]);
    }
    float rr = sigm(dir+bih[t]     + dhr+bhh[t]);
    float zz = sigm(diz+bih[256+t] + dhz+bhh[256+t]);
    float gg = tanhf(dig+bih[512+t] + rr*(dhg+bhh[512+t]));
    nw = (1.f-zz)*gg + zz*rep_s[t];
  }
  // residual LN
  {
    float mu = blkSum(nw, s4)*(1.0f/256.0f);
    float df = nw - mu;
    float var = blkSum(df*df, s4)*(1.0f/256.0f);
    float rs = rsqrtf(var+1e-5f);
    __syncthreads();
    ln_s[t] = df*rs*ln_rg[t]+ln_rb[t];
  }
  __syncthreads();
  // stage 4: MLP
  #pragma unroll
  for(int pq=0;pq<4;pq++){
    int j = pq*256+t;
    float a0=0,a1=0;
    for(int k=0;k<256;k+=2){
      a0 += ln_s[k  ]*bf2f(W1b[(k  )*1024+j]);
      a1 += ln_s[k+1]*bf2f(W1b[(k+1)*1024+j]);
    }
    h1_s[j] = fmaxf(a0+a1, 0.f);
  }
  __syncthreads();
  float rn;
  {
    float a0=0,a1=0,a2=0,a3=0;
    for(int k=0;k<1024;k+=4){
      a0 += h1_s[k  ]*bf2f(W2b[(k  )*256+t]);
      a1 += h1_s[k+1]*bf2f(W2b[(k+1)*256+t]);
      a2 += h1_s[k+2]*bf2f(W2b[(k+2)*256+t]);
      a3 += h1_s[k+3]*bf2f(W2b[(k+3)*256+t]);
    }
    rn = nw + (a0+a1+a2+a3) + b2[t];
  }
  rep[b*256+t] = rn;
  if (last){ out_rep[b*256+t] = rn; return; }
  // stage 5: slot-LN -> q -> p
  {
    float mu = blkSum(rn, s4)*(1.0f/256.0f);
    float df = rn - mu;
    float var = blkSum(df*df, s4)*(1.0f/256.0f);
    float rs = rsqrtf(var+1e-5f);
    __syncthreads();
    ln_s[t] = df*rs*ln_sg[t]+ln_sb[t];
  }
  __syncthreads();
  {
    float a0=0,a1=0,a2=0,a3=0;
    for(int k=0;k<256;k+=4){
      a0 += ln_s[k  ]*bf2f(Wqb[(k  )*256+t]);
      a1 += ln_s[k+1]*bf2f(Wqb[(k+1)*256+t]);
      a2 += ln_s[k+2]*bf2f(Wqb[(k+2)*256+t]);
      a3 += ln_s[k+3]*bf2f(Wqb[(k+3)*256+t]);
    }
    q_s[t] = a0+a1+a2+a3;
  }
  __syncthreads();
  #pragma unroll
  for(int h=0;h<4;h++){
    float p0=0,p1=0;
    for(int d=0;d<64;d+=2){
      p0 += WkT[(h*64+d  )*256 + t]*q_s[h*64+d  ];
      p1 += WkT[(h*64+d+1)*256 + t]*q_s[h*64+d+1];
    }
    p_out[b*1024 + h*256 + t] = 2.0f*(p0+p1);
  }
}

// ---------------- final w output ------------------------------------------
__global__ __launch_bounds__(256) void k_wout(
    const float* __restrict__ w_buf, const float* __restrict__ wsum_tot,
    float* __restrict__ out){
  int idx = blockIdx.x*256 + threadIdx.x;     // 0..524287
  int b = idx>>12;
  float4 w4 = *reinterpret_cast<const float4*>(w_buf + (size_t)idx*4);
  out[idx] = w4.x/wsum_tot[b*4+0] + w4.y/wsum_tot[b*4+1]
           + w4.z/wsum_tot[b*4+2] + w4.w/wsum_tot[b*4+3];
}

extern "C" void kernel_launch(void* const* d_in, const int* in_sizes, int n_in,
                              void* d_out, int out_size, void* d_ws, size_t ws_size,
                              hipStream_t stream){
  const float* inputs  = (const float*)d_in[0];
  const float* eps     = (const float*)d_in[1];
  const float* init_mu = (const float*)d_in[2];
  const float* init_lv = (const float*)d_in[3];
  const float* Wk      = (const float*)d_in[4];
  const float* Wv      = (const float*)d_in[5];
  const float* Wq      = (const float*)d_in[6];
  const float* ln_in_g = (const float*)d_in[7];
  const float* ln_in_b = (const float*)d_in[8];
  const float* ln_sg   = (const float*)d_in[9];
  const float* ln_sb   = (const float*)d_in[10];
  const float* ln_rg   = (const float*)d_in[11];
  const float* ln_rb   = (const float*)d_in[12];
  const float* Wih     = (const float*)d_in[13];
  const float* Whh     = (const float*)d_in[14];
  const float* bih     = (const float*)d_in[15];
  const float* bhh     = (const float*)d_in[16];
  const float* W1      = (const float*)d_in[17];
  const float* W2      = (const float*)d_in[18];
  const float* b2      = (const float*)d_in[19];

  char* ws = (char*)d_ws;
  size_t off = 0;
  auto alloc = [&](size_t bytes)->void*{
    void* p = ws + off; off += (bytes + 255) & ~(size_t)255; return p;
  };
  unsigned short* x    = (unsigned short*)alloc((size_t)128*N_*256*2);
  float*          WkT  = (float*)alloc(256*256*4);
  unsigned short* WihT = (unsigned short*)alloc(256*768*2);
  unsigned short* WhhT = (unsigned short*)alloc(256*768*2);
  unsigned short* W1b  = (unsigned short*)alloc(256*1024*2);
  unsigned short* W2b  = (unsigned short*)alloc(1024*256*2);
  unsigned short* Wqb  = (unsigned short*)alloc(256*256*2);
  float* p_buf    = (float*)alloc((size_t)128*1024*4);
  float* u_part   = (float*)alloc((size_t)NSPLIT*128*1024*4);
  float* ws_part  = (float*)alloc((size_t)NSPLIT*128*4*4);
  float* wsum_tot = (float*)alloc(512*4);
  float* rep      = (float*)alloc(128*256*4);
  float* w_buf    = (float*)alloc((size_t)128*N_*4*4);

  float* out_rep = (float*)d_out;
  float* out_w   = out_rep + 128*256;

  k_prep<<<1024,256,0,stream>>>(Wk,Wih,Whh,W1,W2,Wq, WkT,WihT,WhhT,W1b,W2b,Wqb);
  k_ln_in<<<131072,256,0,stream>>>(inputs, ln_in_g, ln_in_b, x);
  k_init<<<128,256,0,stream>>>(eps, init_mu, init_lv, ln_sg, ln_sb, Wqb, WkT, rep, p_buf);
  for(int t=0;t<4;t++){
    int last = (t==3) ? 1 : 0;
    k_attn<<<dim3(NSPLIT,128),256,0,stream>>>(x, p_buf, u_part, ws_part, w_buf, last);
    k_step<<<128,256,0,stream>>>(u_part, ws_part, Wv, WihT, WhhT, bih, bhh,
                                 ln_rg, ln_rb, W1b, W2b, b2, ln_sg, ln_sb,
                                 Wqb, WkT, rep, p_buf, wsum_tot, out_rep, last);
  }
  k_wout<<<2048,256,0,stream>>>(w_buf, wsum_tot, out_w);
}

// Round 3
// 699.144 us; speedup vs baseline: 2.2798x; 1.2938x over previous
//
#include <hip/hip_runtime.h>
#include <hip/hip_bf16.h>

typedef __attribute__((ext_vector_type(2))) float f32x2;
typedef __attribute__((ext_vector_type(8))) unsigned short ushort8;
typedef __attribute__((ext_vector_type(4))) unsigned short ushort4_t;

#define N_    4096
#define NSPLIT 16

__device__ inline float bf2f(unsigned short u){
  union{unsigned int i; float f;} c; c.i = ((unsigned int)u)<<16; return c.f;
}
__device__ inline unsigned short f2bf(float f){
  union{float f; unsigned int i;} c; c.f = f;
  unsigned int x = c.i;
  return (unsigned short)((x + 0x7fffu + ((x>>16)&1u)) >> 16);
}
__device__ inline float sigm(float s){ return 1.0f/(1.0f+__expf(-s)); }
__device__ inline f32x2 up2(unsigned int w){
  union{unsigned int i; float f;} lo, hi;
  lo.i = w<<16; hi.i = w & 0xffff0000u;
  f32x2 r; r.x = lo.f; r.y = hi.f; return r;
}

// block = 256 threads (4 waves). Full block sum.
__device__ inline float blkSum(float v, float* s4){
  v += __shfl_xor(v,1);  v += __shfl_xor(v,2);  v += __shfl_xor(v,4);
  v += __shfl_xor(v,8);  v += __shfl_xor(v,16); v += __shfl_xor(v,32);
  int lane = threadIdx.x & 63, w = threadIdx.x >> 6;
  __syncthreads();
  if (lane==0) s4[w] = v;
  __syncthreads();
  return s4[0]+s4[1]+s4[2]+s4[3];
}

// block = 1024 threads (16 waves). Full block sum.
__device__ inline float blkSum16(float v, float* s16){
  #pragma unroll
  for(int o=1;o<64;o<<=1) v += __shfl_xor(v,o);
  int lane = threadIdx.x & 63, w = threadIdx.x >> 6;
  __syncthreads();
  if (lane==0) s16[w] = v;
  __syncthreads();
  float r = 0.f;
  #pragma unroll
  for(int i=0;i<16;i++) r += s16[i];
  return r;
}

// ---------------- prep: weight transposes / bf16 casts --------------------
__global__ __launch_bounds__(256) void k_prep(
    const float* __restrict__ Wk, const float* __restrict__ Wih,
    const float* __restrict__ Whh, const float* __restrict__ W1,
    const float* __restrict__ W2, const float* __restrict__ Wq,
    float* __restrict__ WkT, unsigned short* __restrict__ WihT,
    unsigned short* __restrict__ WhhT, unsigned short* __restrict__ W1b,
    unsigned short* __restrict__ W2b, unsigned short* __restrict__ Wqb){
  int idx = blockIdx.x*256 + threadIdx.x;          // 0 .. 262143
  if (idx < 256*256){                               // WkT[d][c] = Wk[c][d] (f32)
    int d = idx>>8, c = idx&255;
    WkT[idx] = Wk[c*256+d];
    Wqb[idx] = f2bf(Wq[idx]);
  }
  if (idx < 256*768){                               // WihT/WhhT [256 k][768 j]
    int k = idx/768, j = idx - k*768;
    WihT[idx] = f2bf(Wih[j*256+k]);
    WhhT[idx] = f2bf(Whh[j*256+k]);
  }
  if (idx < 256*1024){ W1b[idx] = f2bf(W1[idx]); W2b[idx] = f2bf(W2[idx]); }
}

// ---------------- init: rep0 = mu + exp(.5 lv)*eps ; q0 -> p0 -------------
__global__ __launch_bounds__(256) void k_init(
    const float* __restrict__ eps, const float* __restrict__ mu0,
    const float* __restrict__ lv0, const float* __restrict__ sg,
    const float* __restrict__ sb, const unsigned short* __restrict__ Wqb,
    const float* __restrict__ WkT,
    float* __restrict__ rep, float* __restrict__ p_out){
  __shared__ float s4[4]; __shared__ float xq[256]; __shared__ float q_s[256];
  int b = blockIdx.x, c = threadIdx.x;
  float r0 = mu0[c] + __expf(0.5f*lv0[c]) * eps[b*256+c];
  rep[b*256+c] = r0;
  float mu = blkSum(r0, s4) * (1.0f/256.0f);
  float df = r0 - mu;
  float var = blkSum(df*df, s4) * (1.0f/256.0f);
  float rs = rsqrtf(var + 1e-5f);
  xq[c] = df*rs*sg[c] + sb[c];
  __syncthreads();
  float a0=0,a1=0,a2=0,a3=0;
  for(int k=0;k<256;k+=4){
    a0 += xq[k  ]*bf2f(Wqb[(k  )*256+c]);
    a1 += xq[k+1]*bf2f(Wqb[(k+1)*256+c]);
    a2 += xq[k+2]*bf2f(Wqb[(k+2)*256+c]);
    a3 += xq[k+3]*bf2f(Wqb[(k+3)*256+c]);
  }
  q_s[c] = a0+a1+a2+a3;
  __syncthreads();
  #pragma unroll
  for(int h=0;h<4;h++){
    float p0=0,p1=0;
    for(int d=0;d<64;d+=2){
      p0 += WkT[(h*64+d  )*256 + c]*q_s[h*64+d  ];
      p1 += WkT[(h*64+d+1)*256 + c]*q_s[h*64+d+1];
    }
    p_out[b*1024 + h*256 + c] = 2.0f*(p0+p1);
  }
}

// ---------------- fused input-LN + attention pass 1 -----------------------
// Each block: one (split,b); 256 rows; wave per row, lane owns c=lane*4..+3.
__global__ __launch_bounds__(256) void k_lnattn(
    const float* __restrict__ in, const float* __restrict__ g,
    const float* __restrict__ bln, const float* __restrict__ p,
    unsigned short* __restrict__ x,
    float* __restrict__ u_part, float* __restrict__ ws_part){
  int split = blockIdx.x;          // 0..15
  int b     = blockIdx.y;          // 0..127
  int tid = threadIdx.x, wid = tid>>6, lane = tid&63;
  const float* pb = p + (size_t)b*1024;
  float4 pp[4];
  #pragma unroll
  for(int h=0;h<4;h++) pp[h] = *reinterpret_cast<const float4*>(pb + h*256 + lane*4);
  float4 gg = reinterpret_cast<const float4*>(g)[lane];
  float4 bb = reinterpret_cast<const float4*>(bln)[lane];
  float4 u[4];
  #pragma unroll
  for(int h=0;h<4;h++){ u[h].x=0; u[h].y=0; u[h].z=0; u[h].w=0; }
  float wsum[4] = {0,0,0,0};
  const float* inb = in + ((size_t)b*N_ + split*256)*256;
  unsigned short* xb = x + ((size_t)b*N_ + split*256)*256;
  for(int it=0; it<64; ++it){
    int r = it*4 + wid;
    float4 v = *reinterpret_cast<const float4*>(inb + (size_t)r*256 + lane*4);
    float sm = v.x+v.y+v.z+v.w;
    float sq = v.x*v.x+v.y*v.y+v.z*v.z+v.w*v.w;
    #pragma unroll
    for(int o=1;o<64;o<<=1){ sm += __shfl_xor(sm,o); sq += __shfl_xor(sq,o); }
    float mu = sm*(1.0f/256.0f);
    float var = sq*(1.0f/256.0f) - mu*mu;
    float rs = rsqrtf(var + 1e-5f);
    float4 xv;
    xv.x = (v.x-mu)*rs*gg.x + bb.x;
    xv.y = (v.y-mu)*rs*gg.y + bb.y;
    xv.z = (v.z-mu)*rs*gg.z + bb.z;
    xv.w = (v.w-mu)*rs*gg.w + bb.w;
    ushort4_t o4;
    o4.x = f2bf(xv.x); o4.y = f2bf(xv.y); o4.z = f2bf(xv.z); o4.w = f2bf(xv.w);
    reinterpret_cast<ushort4_t*>(xb + (size_t)r*256)[lane] = o4;
    #pragma unroll
    for(int h=0;h<4;h++){
      float d = xv.x*pp[h].x + xv.y*pp[h].y + xv.z*pp[h].z + xv.w*pp[h].w;
      #pragma unroll
      for(int o=1;o<64;o<<=1) d += __shfl_xor(d,o);
      float w = sigm(d) + 1e-8f;
      wsum[h] += w;
      u[h].x += w*xv.x; u[h].y += w*xv.y; u[h].z += w*xv.z; u[h].w += w*xv.w;
    }
  }
  __shared__ float u_lds[4*4*256];   // [wid][h][c]
  __shared__ float ws_lds[4][4];
  #pragma unroll
  for(int h=0;h<4;h++)
    *reinterpret_cast<float4*>(&u_lds[wid*1024 + h*256 + lane*4]) = u[h];
  if (lane==0){
    #pragma unroll
    for(int h=0;h<4;h++) ws_lds[wid][h] = wsum[h];
  }
  __syncthreads();
  {
    int h = tid>>6, c0 = (tid&63)*4;
    float4 s0 = *reinterpret_cast<const float4*>(&u_lds[   0 + h*256 + c0]);
    float4 s1 = *reinterpret_cast<const float4*>(&u_lds[1024 + h*256 + c0]);
    float4 s2 = *reinterpret_cast<const float4*>(&u_lds[2048 + h*256 + c0]);
    float4 s3 = *reinterpret_cast<const float4*>(&u_lds[3072 + h*256 + c0]);
    float4 r; r.x=s0.x+s1.x+s2.x+s3.x; r.y=s0.y+s1.y+s2.y+s3.y;
    r.z=s0.z+s1.z+s2.z+s3.z; r.w=s0.w+s1.w+s2.w+s3.w;
    *reinterpret_cast<float4*>(u_part + (((size_t)split*128+b)*4+h)*256 + c0) = r;
  }
  if (tid<4)
    ws_part[((size_t)split*128+b)*4 + tid] =
      ws_lds[0][tid]+ws_lds[1][tid]+ws_lds[2][tid]+ws_lds[3][tid];
}

// ---------------- attention passes 2..4 on x (bf16) -----------------------
__global__ __launch_bounds__(256) void k_attn(
    const unsigned short* __restrict__ x, const float* __restrict__ p,
    float* __restrict__ u_part, float* __restrict__ ws_part,
    float* __restrict__ w_out, int write_w){
  int split = blockIdx.x;          // 0..15
  int b     = blockIdx.y;          // 0..127
  int tid = threadIdx.x, wid = tid>>6, lane = tid&63;
  int rgrp = lane>>4, cl = lane&15;
  const float* pb = p + (size_t)b*1024;
  f32x2 pp[4][2][4];
  #pragma unroll
  for(int h=0;h<4;h++)
    #pragma unroll
    for(int qq=0;qq<2;qq++){
      const float4 a = *reinterpret_cast<const float4*>(pb + h*256 + qq*128 + cl*8);
      const float4 c = *reinterpret_cast<const float4*>(pb + h*256 + qq*128 + cl*8 + 4);
      pp[h][qq][0] = f32x2{a.x,a.y}; pp[h][qq][1] = f32x2{a.z,a.w};
      pp[h][qq][2] = f32x2{c.x,c.y}; pp[h][qq][3] = f32x2{c.z,c.w};
    }
  f32x2 u[4][2][4] = {};
  float wsum[4] = {0,0,0,0};
  const unsigned short* xb = x + (size_t)b*N_*256;
  for(int it=0; it<16; ++it){
    int n = (split<<8) + (it<<4) + (wid<<2) + rgrp;
    const unsigned short* xr = xb + (size_t)n*256;
    uint4 xa = *reinterpret_cast<const uint4*>(xr + cl*8);
    uint4 xc = *reinterpret_cast<const uint4*>(xr + 128 + cl*8);
    f32x2 xf[2][4];
    xf[0][0]=up2(xa.x); xf[0][1]=up2(xa.y); xf[0][2]=up2(xa.z); xf[0][3]=up2(xa.w);
    xf[1][0]=up2(xc.x); xf[1][1]=up2(xc.y); xf[1][2]=up2(xc.z); xf[1][3]=up2(xc.w);
    float w[4];
    #pragma unroll
    for(int h=0;h<4;h++){
      f32x2 d2 = xf[0][0]*pp[h][0][0];
      d2 += xf[0][1]*pp[h][0][1];
      d2 += xf[0][2]*pp[h][0][2];
      d2 += xf[0][3]*pp[h][0][3];
      d2 += xf[1][0]*pp[h][1][0];
      d2 += xf[1][1]*pp[h][1][1];
      d2 += xf[1][2]*pp[h][1][2];
      d2 += xf[1][3]*pp[h][1][3];
      float s = d2.x + d2.y;
      s += __shfl_xor(s,1); s += __shfl_xor(s,2);
      s += __shfl_xor(s,4); s += __shfl_xor(s,8);
      w[h] = sigm(s) + 1e-8f;
      wsum[h] += w[h];
    }
    #pragma unroll
    for(int h=0;h<4;h++){
      f32x2 w2; w2.x = w[h]; w2.y = w[h];
      #pragma unroll
      for(int qq=0;qq<2;qq++){
        u[h][qq][0] += w2*xf[qq][0];
        u[h][qq][1] += w2*xf[qq][1];
        u[h][qq][2] += w2*xf[qq][2];
        u[h][qq][3] += w2*xf[qq][3];
      }
    }
    if (write_w && cl==0){
      float4 wv; wv.x=w[0]; wv.y=w[1]; wv.z=w[2]; wv.w=w[3];
      *reinterpret_cast<float4*>(w_out + ((size_t)b*N_ + n)*4) = wv;
    }
  }
  #pragma unroll
  for(int h=0;h<4;h++){
    #pragma unroll
    for(int qq=0;qq<2;qq++)
      #pragma unroll
      for(int j=0;j<4;j++){
        f32x2 v = u[h][qq][j];
        v.x += __shfl_xor(v.x,16); v.y += __shfl_xor(v.y,16);
        v.x += __shfl_xor(v.x,32); v.y += __shfl_xor(v.y,32);
        u[h][qq][j] = v;
      }
    wsum[h] += __shfl_xor(wsum[h],16);
    wsum[h] += __shfl_xor(wsum[h],32);
  }
  __shared__ float u_lds[4*4*256];
  __shared__ float ws_lds[4][4];
  if (rgrp==0){   // lanes 0..15
    #pragma unroll
    for(int h=0;h<4;h++){
      #pragma unroll
      for(int qq=0;qq<2;qq++)
        #pragma unroll
        for(int j=0;j<4;j++){
          int c = qq*128 + cl*8 + j*2;
          u_lds[wid*1024 + h*256 + c    ] = u[h][qq][j].x;
          u_lds[wid*1024 + h*256 + c + 1] = u[h][qq][j].y;
        }
      if (lane==0) ws_lds[wid][h] = wsum[h];
    }
  }
  __syncthreads();
  {
    int h = tid>>6, c0 = (tid&63)*4;
    float4 s0 = *reinterpret_cast<const float4*>(u_lds +    0 + h*256 + c0);
    float4 s1 = *reinterpret_cast<const float4*>(u_lds + 1024 + h*256 + c0);
    float4 s2 = *reinterpret_cast<const float4*>(u_lds + 2048 + h*256 + c0);
    float4 s3 = *reinterpret_cast<const float4*>(u_lds + 3072 + h*256 + c0);
    float4 r; r.x=s0.x+s1.x+s2.x+s3.x; r.y=s0.y+s1.y+s2.y+s3.y;
    r.z=s0.z+s1.z+s2.z+s3.z; r.w=s0.w+s1.w+s2.w+s3.w;
    *reinterpret_cast<float4*>(u_part + (((size_t)split*128+b)*4+h)*256 + c0) = r;
  }
  if (tid<4)
    ws_part[((size_t)split*128+b)*4 + tid] =
      ws_lds[0][tid]+ws_lds[1][tid]+ws_lds[2][tid]+ws_lds[3][tid];
}

// ---------------- fused step (1024 threads, k-sliced GEMVs) ---------------
__global__ __launch_bounds__(1024) void k_step(
    const float* __restrict__ u_part, const float* __restrict__ ws_part,
    const float* __restrict__ Wv, const unsigned short* __restrict__ WihT,
    const unsigned short* __restrict__ WhhT, const float* __restrict__ bih,
    const float* __restrict__ bhh, const float* __restrict__ ln_rg,
    const float* __restrict__ ln_rb, const unsigned short* __restrict__ W1b,
    const unsigned short* __restrict__ W2b, const float* __restrict__ b2,
    const float* __restrict__ ln_sg, const float* __restrict__ ln_sb,
    const unsigned short* __restrict__ Wqb, const float* __restrict__ WkT,
    float* __restrict__ rep, float* __restrict__ p_out,
    float* __restrict__ wsum_tot, float* __restrict__ out_rep, int last){
  __shared__ float u_s[1024];
  __shared__ float att_s[256];
  __shared__ float rep_s[256];
  __shared__ float ln_s[256];
  __shared__ float h1_s[1024];
  __shared__ float q_s[256];
  __shared__ float nw_s[256];
  __shared__ float red_a[1024];
  __shared__ float red_b[1024];
  __shared__ float ws_s[4];
  __shared__ float s16[16];
  int b = blockIdx.x, t = threadIdx.x;
  int c = t & 255, s = t >> 8;            // s = k-slice 0..3
  // stage 1: sum u over splits
  {
    float acc = 0.f;
    #pragma unroll
    for(int sp=0;sp<NSPLIT;sp++)
      acc += u_part[(((size_t)sp*128+b)*4+s)*256 + c];
    u_s[s*256+c] = acc;
    if (t < 4){
      float w=0.f;
      #pragma unroll
      for(int sp=0;sp<NSPLIT;sp++) w += ws_part[((size_t)sp*128+b)*4 + t];
      ws_s[t]=w; wsum_tot[b*4+t]=w;
    }
    if (s==0) rep_s[c] = rep[b*256+c];
  }
  __syncthreads();
  // stage 2: att = (u . Wv)/ws  — k-sliced
  {
    int h = c>>6;
    const float* us = u_s + h*256 + s*64;
    float a0=0,a1=0;
    for(int k=0;k<64;k+=2){
      a0 += us[k  ]*Wv[(s*64+k  )*256+c];
      a1 += us[k+1]*Wv[(s*64+k+1)*256+c];
    }
    red_a[t] = a0+a1;
  }
  __syncthreads();
  if (s==0) att_s[c] = (red_a[c]+red_a[256+c]+red_a[512+c]+red_a[768+c]) / ws_s[c>>6];
  __syncthreads();
  // stage 3: GRU — k-sliced, two reduce rounds
  float rsum=0.f, zsum=0.f;
  {
    float dir=0,dhr=0,diz=0,dhz=0,dig=0,dhg=0;
    for(int kk=0;kk<64;kk++){
      int k = s*64+kk;
      float a = att_s[k], r = rep_s[k];
      const unsigned short* wi = WihT + k*768;
      const unsigned short* wh = WhhT + k*768;
      dir += a*bf2f(wi[c]);      dhr += r*bf2f(wh[c]);
      diz += a*bf2f(wi[256+c]);  dhz += r*bf2f(wh[256+c]);
      dig += a*bf2f(wi[512+c]);  dhg += r*bf2f(wh[512+c]);
    }
    red_a[t] = dir+dhr; red_b[t] = diz+dhz;
    __syncthreads();
    if (s==0){
      rsum = red_a[c]+red_a[256+c]+red_a[512+c]+red_a[768+c];
      zsum = red_b[c]+red_b[256+c]+red_b[512+c]+red_b[768+c];
    }
    __syncthreads();
    red_a[t] = dig; red_b[t] = dhg;
    __syncthreads();
    if (s==0){
      float ig = red_a[c]+red_a[256+c]+red_a[512+c]+red_a[768+c];
      float hg = red_b[c]+red_b[256+c]+red_b[512+c]+red_b[768+c];
      float rr = sigm(rsum + bih[c]     + bhh[c]);
      float zz = sigm(zsum + bih[256+c] + bhh[256+c]);
      float gg = tanhf(ig + bih[512+c] + rr*(hg + bhh[512+c]));
      nw_s[c] = (1.f-zz)*gg + zz*rep_s[c];
    }
    __syncthreads();
  }
  // residual LN (all 1024 threads; each value counted 4x)
  {
    float v = nw_s[c];
    float mu = blkSum16(v, s16)*(1.0f/1024.0f);
    float df = v - mu;
    float var = blkSum16(df*df, s16)*(1.0f/1024.0f);
    float rs = rsqrtf(var+1e-5f);
    if (s==0) ln_s[c] = df*rs*ln_rg[c]+ln_rb[c];
    __syncthreads();
  }
  // stage 4: MLP W1 (one j per thread)
  {
    float a0=0,a1=0;
    for(int k=0;k<256;k+=2){
      a0 += ln_s[k  ]*bf2f(W1b[(k  )*1024+t]);
      a1 += ln_s[k+1]*bf2f(W1b[(k+1)*1024+t]);
    }
    h1_s[t] = fmaxf(a0+a1, 0.f);
  }
  __syncthreads();
  // W2 — k-sliced over 1024
  {
    float a0=0,a1=0;
    for(int kk=0;kk<256;kk+=2){
      int k = s*256+kk;
      a0 += h1_s[k  ]*bf2f(W2b[(k  )*256+c]);
      a1 += h1_s[k+1]*bf2f(W2b[(k+1)*256+c]);
    }
    red_a[t] = a0+a1;
  }
  __syncthreads();
  if (s==0){
    float rn = nw_s[c] + (red_a[c]+red_a[256+c]+red_a[512+c]+red_a[768+c]) + b2[c];
    rep[b*256+c] = rn;
    if (last) out_rep[b*256+c] = rn;
    nw_s[c] = rn;
  }
  __syncthreads();
  if (last) return;
  // slot-LN
  {
    float v = nw_s[c];
    float mu = blkSum16(v, s16)*(1.0f/1024.0f);
    float df = v - mu;
    float var = blkSum16(df*df, s16)*(1.0f/1024.0f);
    float rs = rsqrtf(var+1e-5f);
    if (s==0) ln_s[c] = df*rs*ln_sg[c]+ln_sb[c];
    __syncthreads();
  }
  // q — k-sliced
  {
    float a0=0,a1=0;
    for(int kk=0;kk<64;kk+=2){
      int k = s*64+kk;
      a0 += ln_s[k  ]*bf2f(Wqb[(k  )*256+c]);
      a1 += ln_s[k+1]*bf2f(Wqb[(k+1)*256+c]);
    }
    red_a[t] = a0+a1;
  }
  __syncthreads();
  if (s==0) q_s[c] = red_a[c]+red_a[256+c]+red_a[512+c]+red_a[768+c];
  __syncthreads();
  // p: thread t -> (h=s, c)
  {
    float p0=0,p1=0;
    for(int d=0;d<64;d+=2){
      p0 += WkT[(s*64+d  )*256 + c]*q_s[s*64+d  ];
      p1 += WkT[(s*64+d+1)*256 + c]*q_s[s*64+d+1];
    }
    p_out[b*1024 + t] = 2.0f*(p0+p1);
  }
}

// ---------------- final w output ------------------------------------------
__global__ __launch_bounds__(256) void k_wout(
    const float* __restrict__ w_buf, const float* __restrict__ wsum_tot,
    float* __restrict__ out){
  int idx = blockIdx.x*256 + threadIdx.x;     // 0..524287
  int b = idx>>12;
  float4 w4 = *reinterpret_cast<const float4*>(w_buf + (size_t)idx*4);
  out[idx] = w4.x/wsum_tot[b*4+0] + w4.y/wsum_tot[b*4+1]
           + w4.z/wsum_tot[b*4+2] + w4.w/wsum_tot[b*4+3];
}

extern "C" void kernel_launch(void* const* d_in, const int* in_sizes, int n_in,
                              void* d_out, int out_size, void* d_ws, size_t ws_size,
                              hipStream_t stream){
  const float* inputs  = (const float*)d_in[0];
  const float* eps     = (const float*)d_in[1];
  const float* init_mu = (const float*)d_in[2];
  const float* init_lv = (const float*)d_in[3];
  const float* Wk      = (const float*)d_in[4];
  const float* Wv      = (const float*)d_in[5];
  const float* Wq      = (const float*)d_in[6];
  const float* ln_in_g = (const float*)d_in[7];
  const float* ln_in_b = (const float*)d_in[8];
  const float* ln_sg   = (const float*)d_in[9];
  const float* ln_sb   = (const float*)d_in[10];
  const float* ln_rg   = (const float*)d_in[11];
  const float* ln_rb   = (const float*)d_in[12];
  const float* Wih     = (const float*)d_in[13];
  const float* Whh     = (const float*)d_in[14];
  const float* bih     = (const float*)d_in[15];
  const float* bhh     = (const float*)d_in[16];
  const float* W1      = (const float*)d_in[17];
  const float* W2      = (const float*)d_in[18];
  const float* b2      = (const float*)d_in[19];

  char* ws = (char*)d_ws;
  size_t off = 0;
  auto alloc = [&](size_t bytes)->void*{
    void* p = ws + off; off += (bytes + 255) & ~(size_t)255; return p;
  };
  unsigned short* x    = (unsigned short*)alloc((size_t)128*N_*256*2);
  float*          WkT  = (float*)alloc(256*256*4);
  unsigned short* WihT = (unsigned short*)alloc(256*768*2);
  unsigned short* WhhT = (unsigned short*)alloc(256*768*2);
  unsigned short* W1b  = (unsigned short*)alloc(256*1024*2);
  unsigned short* W2b  = (unsigned short*)alloc(1024*256*2);
  unsigned short* Wqb  = (unsigned short*)alloc(256*256*2);
  float* p_buf    = (float*)alloc((size_t)128*1024*4);
  float* u_part   = (float*)alloc((size_t)NSPLIT*128*1024*4);
  float* ws_part  = (float*)alloc((size_t)NSPLIT*128*4*4);
  float* wsum_tot = (float*)alloc(512*4);
  float* rep      = (float*)alloc(128*256*4);
  float* w_buf    = (float*)alloc((size_t)128*N_*4*4);

  float* out_rep = (float*)d_out;
  float* out_w   = out_rep + 128*256;

  k_prep<<<1024,256,0,stream>>>(Wk,Wih,Whh,W1,W2,Wq, WkT,WihT,WhhT,W1b,W2b,Wqb);
  k_init<<<128,256,0,stream>>>(eps, init_mu, init_lv, ln_sg, ln_sb, Wqb, WkT, rep, p_buf);
  k_lnattn<<<dim3(NSPLIT,128),256,0,stream>>>(inputs, ln_in_g, ln_in_b, p_buf,
                                              x, u_part, ws_part);
  for(int t=0;t<4;t++){
    int last = (t==3) ? 1 : 0;
    if (t>0)
      k_attn<<<dim3(NSPLIT,128),256,0,stream>>>(x, p_buf, u_part, ws_part, w_buf, last);
    k_step<<<128,1024,0,stream>>>(u_part, ws_part, Wv, WihT, WhhT, bih, bhh,
                                  ln_rg, ln_rb, W1b, W2b, b2, ln_sg, ln_sb,
                                  Wqb, WkT, rep, p_buf, wsum_tot, out_rep, last);
  }
  k_wout<<<2048,256,0,stream>>>(w_buf, wsum_tot, out_w);
}